// Round 2
// baseline (1331.499 us; speedup 1.0000x reference)
//
#include <hip/hip_runtime.h>

// DecorrelationNormalization (group whitening), x: [32,64,64,256] f32 NHWC.
// N = 131072 rows, C = 256 channels, 16 groups of m=16.
// R2: coalesced lane mapping — lane l -> group (l&15), row-slot (l>>4).
// Per load instruction a wave covers 4 full rows (4 KB contiguous).

#define NROWS   131072
#define DENOMF  131071.0f
#define EPSV    0.001f

// workspace float offsets
#define OFF_TRI  0        // [16][136] Sxx upper-triangle sums
#define OFF_SX   2176     // [256] channel sums
#define OFF_INV  2432     // [16][16][16] inv_sqrt rows (upper filled w/ 0)
#define OFF_BIAS 6528     // [16][16] bias_i = sum_k inv[i][k]*mu[k]
#define ACC_FLOATS 2432   // region that must be zeroed before k1

// ---------------- Phase 1: stats ----------------
// grid 512 x 256 = 2048 waves. Wave W owns rows [W*64, W*64+64).
// Per pass: lane handles row base+pass*4+slot, its own group's 16 channels.
__global__ __launch_bounds__(256, 2) void k1_stats(const float* __restrict__ x,
                                                   float* __restrict__ ws) {
    const int tid  = threadIdx.x;
    const int wv   = tid >> 6;
    const int lane = tid & 63;
    const int g    = lane & 15;
    const int slot = lane >> 4;
    const int W    = blockIdx.x * 4 + wv;
    const size_t rowbase = (size_t)W * 64;

    float acc[136];
    float s[16];
#pragma unroll
    for (int p = 0; p < 136; ++p) acc[p] = 0.0f;
#pragma unroll
    for (int k = 0; k < 16; ++k) s[k] = 0.0f;

    for (int pass = 0; pass < 16; ++pass) {
        size_t row = rowbase + (size_t)pass * 4 + slot;
        const float4* p4 = reinterpret_cast<const float4*>(x + row * 256 + g * 16);
        float4 a = p4[0], b = p4[1], c = p4[2], d = p4[3];
        float v[16] = {a.x, a.y, a.z, a.w, b.x, b.y, b.z, b.w,
                       c.x, c.y, c.z, c.w, d.x, d.y, d.z, d.w};
#pragma unroll
        for (int k = 0; k < 16; ++k) s[k] += v[k];
#pragma unroll
        for (int i = 0; i < 16; ++i) {
#pragma unroll
            for (int j = i; j < 16; ++j) {
                const int idx = i * 16 - (i * (i - 1)) / 2 + (j - i);
                acc[idx] = fmaf(v[i], v[j], acc[idx]);
            }
        }
    }

    // reduce across the 4 row-slots sharing each group (lanes l, l+16, l+32, l+48)
#pragma unroll
    for (int p = 0; p < 136; ++p) {
        acc[p] += __shfl_xor(acc[p], 16, 64);
        acc[p] += __shfl_xor(acc[p], 32, 64);
    }
#pragma unroll
    for (int k = 0; k < 16; ++k) {
        s[k] += __shfl_xor(s[k], 16, 64);
        s[k] += __shfl_xor(s[k], 32, 64);
    }
    if (lane < 16) {   // lane == g
#pragma unroll
        for (int p = 0; p < 136; ++p) atomicAdd(&ws[OFF_TRI + g * 136 + p], acc[p]);
#pragma unroll
        for (int k = 0; k < 16; ++k)  atomicAdd(&ws[OFF_SX + g * 16 + k], s[k]);
    }
}

// ---------------- Phase 2: cov -> cholesky -> inverse -> bias ----------------
// 16 blocks (one group each) x 64 threads (unchanged from R1; ~µs).
__global__ void k2_chol(float* __restrict__ ws) {
    const int g    = blockIdx.x;
    const int lane = threadIdx.x;
    const int ii   = lane & 15;
    const float* tri = ws + OFF_TRI + g * 136;
    const float* sx  = ws + OFF_SX + g * 16;
    const float inv_denom = 1.0f / DENOMF;

    const float mu_l = sx[ii] * (1.0f / (float)NROWS);
    const float mu_i = mu_l;

    float arow[16];
#pragma unroll
    for (int k = 0; k < 16; ++k) {
        const int lo = (ii < k) ? ii : k;
        const int hi = (ii < k) ? k : ii;
        float sxx = tri[lo * 16 - (lo * (lo - 1)) / 2 + (hi - lo)];
        float mu_k = __shfl(mu_l, k, 64);
        float cv = (sxx - (float)NROWS * mu_i * mu_k) * inv_denom;   // /(N-1)
        cv = cv * (1.0f - EPSV) + ((k == ii) ? EPSV : 0.0f);         // shrink
        arow[k] = cv * inv_denom;                                    // faithful 2nd /(N-1)
    }

    float lrow[16];
#pragma unroll
    for (int j = 0; j < 16; ++j) {
        float diag = __shfl(arow[j], j, 64);
        float ljj  = sqrtf(diag);
        float lij  = (ii == j) ? ljj : arow[j] / ljj;
        lrow[j] = lij;
#pragma unroll
        for (int k = j + 1; k < 16; ++k) {
            float lkj = __shfl(lij, k, 64);
            arow[k] = fmaf(-lij, lkj, arow[k]);
        }
    }

    float xcol[16];
#pragma unroll
    for (int i2 = 0; i2 < 16; ++i2) {
        float ssum = (ii == i2) ? 1.0f : 0.0f;
#pragma unroll
        for (int k = 0; k < 16; ++k) {
            if (k < i2) {
                float Lik = __shfl(lrow[k], i2, 64);
                ssum = fmaf(-Lik, xcol[k], ssum);
            }
        }
        float Lii = __shfl(lrow[i2], i2, 64);
        xcol[i2] = (i2 >= ii) ? ssum / Lii : 0.0f;
    }

    float* invg = ws + OFF_INV + g * 256;
#pragma unroll
    for (int i2 = 0; i2 < 16; ++i2) {
        if (lane < 16) invg[i2 * 16 + lane] = xcol[i2];
        float bi = xcol[i2] * mu_l;
        bi += __shfl_xor(bi, 1, 64);
        bi += __shfl_xor(bi, 2, 64);
        bi += __shfl_xor(bi, 4, 64);
        bi += __shfl_xor(bi, 8, 64);
        if (lane == 0) ws[OFF_BIAS + g * 16 + i2] = bi;
    }
}

// ---------------- Phase 3: apply out = inv*x - bias ----------------
// grid 1024 x 256 = 4096 waves. Wave W owns rows [W*32, W*32+32); 4 passes of
// 8 rows (2 row-batches amortize each LDS inv read across 2 rows).
// inv staged in LDS at group stride 260 floats (4g mod 32 -> 2-way = free).
__global__ __launch_bounds__(256, 4) void k3_apply(const float* __restrict__ x,
                                                   const float* __restrict__ ws,
                                                   float* __restrict__ out) {
    __shared__ float sinv[16 * 260];

    const int tid = threadIdx.x;
#pragma unroll
    for (int it = 0; it < 4; ++it) {
        int fidx = tid + it * 256;            // float4 index, 0..1023
        int gg = fidx >> 6, q = fidx & 63;
        float4 val = reinterpret_cast<const float4*>(ws + OFF_INV)[fidx];
        *reinterpret_cast<float4*>(&sinv[gg * 260 + q * 4]) = val;
    }

    const int lane = tid & 63;
    const int wv   = tid >> 6;
    const int g    = lane & 15;
    const int slot = lane >> 4;

    float bias[16];
#pragma unroll
    for (int i = 0; i < 16; ++i) bias[i] = ws[OFF_BIAS + g * 16 + i];

    __syncthreads();
    const float* invg = &sinv[g * 260];

    const int W = blockIdx.x * 4 + wv;        // 0..4095
    const size_t rowbase = (size_t)W * 32;

    for (int pass = 0; pass < 4; ++pass) {
        const size_t base = rowbase + (size_t)pass * 8;
        float v[2][16];
#pragma unroll
        for (int rr = 0; rr < 2; ++rr) {
            size_t row = base + rr * 4 + slot;
            const float4* p4 = reinterpret_cast<const float4*>(x + row * 256 + g * 16);
            float4 a = p4[0], b = p4[1], c = p4[2], d = p4[3];
            v[rr][0]=a.x; v[rr][1]=a.y; v[rr][2]=a.z; v[rr][3]=a.w;
            v[rr][4]=b.x; v[rr][5]=b.y; v[rr][6]=b.z; v[rr][7]=b.w;
            v[rr][8]=c.x; v[rr][9]=c.y; v[rr][10]=c.z; v[rr][11]=c.w;
            v[rr][12]=d.x; v[rr][13]=d.y; v[rr][14]=d.z; v[rr][15]=d.w;
        }
        float o[2][16];
#pragma unroll
        for (int i = 0; i < 16; ++i) {
            float o0 = -bias[i];
            float o1 = -bias[i];
#pragma unroll
            for (int kq = 0; kq < 4; ++kq) {
                if (kq <= (i >> 2)) {          // inv is lower-triangular
                    float4 lv = *reinterpret_cast<const float4*>(&invg[i * 16 + kq * 4]);
                    o0 = fmaf(lv.x, v[0][kq * 4 + 0], o0);
                    o0 = fmaf(lv.y, v[0][kq * 4 + 1], o0);
                    o0 = fmaf(lv.z, v[0][kq * 4 + 2], o0);
                    o0 = fmaf(lv.w, v[0][kq * 4 + 3], o0);
                    o1 = fmaf(lv.x, v[1][kq * 4 + 0], o1);
                    o1 = fmaf(lv.y, v[1][kq * 4 + 1], o1);
                    o1 = fmaf(lv.z, v[1][kq * 4 + 2], o1);
                    o1 = fmaf(lv.w, v[1][kq * 4 + 3], o1);
                }
            }
            o[0][i] = o0;
            o[1][i] = o1;
        }
#pragma unroll
        for (int rr = 0; rr < 2; ++rr) {
            size_t row = base + rr * 4 + slot;
            float4* q4 = reinterpret_cast<float4*>(out + row * 256 + g * 16);
            q4[0] = make_float4(o[rr][0],  o[rr][1],  o[rr][2],  o[rr][3]);
            q4[1] = make_float4(o[rr][4],  o[rr][5],  o[rr][6],  o[rr][7]);
            q4[2] = make_float4(o[rr][8],  o[rr][9],  o[rr][10], o[rr][11]);
            q4[3] = make_float4(o[rr][12], o[rr][13], o[rr][14], o[rr][15]);
        }
    }
}

extern "C" void kernel_launch(void* const* d_in, const int* in_sizes, int n_in,
                              void* d_out, int out_size, void* d_ws, size_t ws_size,
                              hipStream_t stream) {
    const float* x = (const float*)d_in[0];
    float* out = (float*)d_out;
    float* ws  = (float*)d_ws;

    hipMemsetAsync(ws, 0, ACC_FLOATS * sizeof(float), stream);

    k1_stats<<<512, 256, 0, stream>>>(x, ws);
    k2_chol <<<16,  64,  0, stream>>>(ws);
    k3_apply<<<1024, 256, 0, stream>>>(x, ws, out);
}

// Round 3
// 510.007 us; speedup vs baseline: 2.6107x; 2.6107x over previous
//
#include <hip/hip_runtime.h>

// DecorrelationNormalization (group whitening), x: [32,64,64,256] f32 NHWC.
// N = 131072 rows of 256 channels (1 KB each), 16 groups of m=16.
// R3: lane l owns channels [4l,4l+4) -> one load instruction == one full
// contiguous 1 KB row. Quad (4 lanes) == one group; float4 exchange via
// shfl_xor(1,2,3). All register arrays indexed compile-time via permuted
// [m][c] layout (absolute col = 4*(q^m)+c resolved in address math only).

#define NROWS   131072
#define DENOMF  131071.0f
#define EPSV    0.001f

// ws float offsets
#define OFF_INV    0        // [16][256] inv_sqrt row-major
#define OFF_BIAS   4096     // [16][16]  bias_i = sum_k inv[i][k]*mu[k]
#define OFF_TRIM   4352     // [2432] combined tri+sx (atomic fallback mode)
#define OFF_PART   8192     // [nblk][2432] per-block partials
#define COMB       2432     // 16*136 tri + 256 sx

__device__ __forceinline__ float4 shfl_xor4(float4 v, int m) {
    float4 r;
    r.x = __shfl_xor(v.x, m, 64);
    r.y = __shfl_xor(v.y, m, 64);
    r.z = __shfl_xor(v.z, m, 64);
    r.w = __shfl_xor(v.w, m, 64);
    return r;
}

// ---------------- Phase 1: stats ----------------
// grid nblk x 512 thr (8 waves). Block owns rows [b*rpb, (b+1)*rpb).
// Wave wv row: base + i*8 + wv. Per row: 1 load + 12 shfl + 64 FMA.
__global__ __launch_bounds__(512, 2) void k1_stats(const float* __restrict__ x,
                                                   float* __restrict__ ws, int nblk) {
    __shared__ float sacc[COMB];        // [0:2176) tri, [2176:2432) sx
    const int tid = threadIdx.x;
    for (int t = tid; t < COMB; t += 512) sacc[t] = 0.0f;
    __syncthreads();

    const int lane = tid & 63, wv = tid >> 6;
    const int q = lane & 3, g = lane >> 2;
    const int rpb   = NROWS / gridDim.x;
    const int iters = rpb / 8;
    const size_t rowbase = (size_t)blockIdx.x * rpb;
    const float4* xp = reinterpret_cast<const float4*>(x) + rowbase * 64 + lane;

    float acc[4][4][4];                 // [jj(own col)][m(xor)][c]
#pragma unroll
    for (int a = 0; a < 4; ++a)
#pragma unroll
        for (int b = 0; b < 4; ++b)
#pragma unroll
            for (int c = 0; c < 4; ++c) acc[a][b][c] = 0.0f;
    float s4[4] = {0.0f, 0.0f, 0.0f, 0.0f};

    float4 cur = xp[(size_t)wv * 64];
    for (int i = 0; i < iters; ++i) {
        float4 nxt;
        if (i + 1 < iters) nxt = xp[(size_t)((i + 1) * 8 + wv) * 64];

        float4 x1 = shfl_xor4(cur, 1);
        float4 x2 = shfl_xor4(cur, 2);
        float4 x3 = shfl_xor4(cur, 3);
        float vm[4][4] = {{cur.x, cur.y, cur.z, cur.w},
                          {x1.x, x1.y, x1.z, x1.w},
                          {x2.x, x2.y, x2.z, x2.w},
                          {x3.x, x3.y, x3.z, x3.w}};
        s4[0] += vm[0][0]; s4[1] += vm[0][1]; s4[2] += vm[0][2]; s4[3] += vm[0][3];
#pragma unroll
        for (int jj = 0; jj < 4; ++jj)
#pragma unroll
            for (int m = 0; m < 4; ++m)
#pragma unroll
                for (int c = 0; c < 4; ++c)
                    acc[jj][m][c] = fmaf(vm[m][c], vm[0][jj], acc[jj][m][c]);
        cur = nxt;
    }

    // fold rectangle into the triangle (i2 <= j only: symmetric partner skips)
#pragma unroll
    for (int jj = 0; jj < 4; ++jj) {
        const int j = 4 * q + jj;
#pragma unroll
        for (int m = 0; m < 4; ++m) {
            const int cb = 4 * (q ^ m);
#pragma unroll
            for (int c = 0; c < 4; ++c) {
                const int i2 = cb + c;
                if (i2 <= j)
                    atomicAdd(&sacc[g * 136 + i2 * 16 - (i2 * (i2 - 1)) / 2 + (j - i2)],
                              acc[jj][m][c]);
            }
        }
        atomicAdd(&sacc[2176 + 4 * lane + jj], s4[jj]);
    }
    __syncthreads();

    if (nblk > 0) {
        float* dst = ws + OFF_PART + (size_t)blockIdx.x * COMB;
        for (int t = tid; t < COMB; t += 512) dst[t] = sacc[t];
    } else {
        for (int t = tid; t < COMB; t += 512) atomicAdd(&ws[OFF_TRIM + t], sacc[t]);
    }
}

// ---------------- Phase 2: reduce partials + cov -> cholesky -> inverse ----------------
// 16 blocks (one group) x 64 threads.
__global__ void k2_chol(float* __restrict__ ws, int nblk) {
    __shared__ float ct[136];
    __shared__ float cs[16];
    const int g = blockIdx.x, tid = threadIdx.x;

    if (nblk > 0) {
        for (int e = tid; e < 152; e += 64) {
            const int src = (e < 136) ? (g * 136 + e) : (2176 + g * 16 + (e - 136));
            const float* p = ws + OFF_PART + src;
            float sum = 0.0f;
            for (int b = 0; b < nblk; ++b) sum += p[(size_t)b * COMB];
            if (e < 136) ct[e] = sum; else cs[e - 136] = sum;
        }
    } else {
        for (int e = tid; e < 152; e += 64) {
            const int src = (e < 136) ? (g * 136 + e) : (2176 + g * 16 + (e - 136));
            float v = ws[OFF_TRIM + src];
            if (e < 136) ct[e] = v; else cs[e - 136] = v;
        }
    }
    __syncthreads();

    const int ii = tid & 15;
    const float inv_denom = 1.0f / DENOMF;
    const float mu_l = cs[ii] * (1.0f / (float)NROWS);

    float arow[16];
#pragma unroll
    for (int k = 0; k < 16; ++k) {
        const int lo = (ii < k) ? ii : k;
        const int hi = (ii < k) ? k : ii;
        float sxx = ct[lo * 16 - (lo * (lo - 1)) / 2 + (hi - lo)];
        float mu_k = __shfl(mu_l, k, 64);
        float cv = (sxx - (float)NROWS * mu_l * mu_k) * inv_denom;   // /(N-1)
        cv = cv * (1.0f - EPSV) + ((k == ii) ? EPSV : 0.0f);         // shrink
        arow[k] = cv * inv_denom;                                    // faithful 2nd /(N-1)
    }

    float lrow[16];
#pragma unroll
    for (int j = 0; j < 16; ++j) {
        float diag = __shfl(arow[j], j, 64);
        float ljj  = sqrtf(diag);
        float lij  = (ii == j) ? ljj : arow[j] / ljj;
        lrow[j] = lij;
#pragma unroll
        for (int k = j + 1; k < 16; ++k) {
            float lkj = __shfl(lij, k, 64);
            arow[k] = fmaf(-lij, lkj, arow[k]);
        }
    }

    float xcol[16];
#pragma unroll
    for (int i2 = 0; i2 < 16; ++i2) {
        float ssum = (ii == i2) ? 1.0f : 0.0f;
#pragma unroll
        for (int k = 0; k < 16; ++k) {
            if (k < i2) {
                float Lik = __shfl(lrow[k], i2, 64);
                ssum = fmaf(-Lik, xcol[k], ssum);
            }
        }
        float Lii = __shfl(lrow[i2], i2, 64);
        xcol[i2] = (i2 >= ii) ? ssum / Lii : 0.0f;
    }

    float* invg = ws + OFF_INV + g * 256;
#pragma unroll
    for (int i2 = 0; i2 < 16; ++i2) {
        if (tid < 16) invg[i2 * 16 + tid] = xcol[i2];
        float bi = xcol[i2] * mu_l;
        bi += __shfl_xor(bi, 1, 64);
        bi += __shfl_xor(bi, 2, 64);
        bi += __shfl_xor(bi, 4, 64);
        bi += __shfl_xor(bi, 8, 64);
        if (tid == 0) ws[OFF_BIAS + g * 16 + i2] = bi;
    }
}

// ---------------- Phase 3: apply out = inv*x - bias ----------------
// grid 1024 x 256 thr (4 waves). Wave row: base + i*4 + wv; 32 rows/wave.
// inv rows 4q..4q+3 held in registers, permuted [r][m][c].
__global__ __launch_bounds__(256, 2) void k3_apply(const float* __restrict__ x,
                                                   const float* __restrict__ ws,
                                                   float* __restrict__ out) {
    const int tid = threadIdx.x, lane = tid & 63, wv = tid >> 6;
    const int q = lane & 3, g = lane >> 2;

    float ir[4][4][4];                  // [r(own row)][m(xor)][c]
    const float* invg = ws + OFF_INV + g * 256;
#pragma unroll
    for (int r = 0; r < 4; ++r)
#pragma unroll
        for (int m = 0; m < 4; ++m) {
            float4 t = *reinterpret_cast<const float4*>(invg + (4 * q + r) * 16 + 4 * (q ^ m));
            ir[r][m][0] = t.x; ir[r][m][1] = t.y; ir[r][m][2] = t.z; ir[r][m][3] = t.w;
        }
    float4 b4 = *reinterpret_cast<const float4*>(ws + OFF_BIAS + g * 16 + 4 * q);

    const int rpb   = NROWS / gridDim.x;   // 128
    const int iters = rpb / 4;             // 32
    const size_t rowbase = (size_t)blockIdx.x * rpb;
    const float4* xp = reinterpret_cast<const float4*>(x) + rowbase * 64 + lane;
    float4*       op = reinterpret_cast<float4*>(out)     + rowbase * 64 + lane;

    float4 cur = xp[(size_t)wv * 64];
    for (int i = 0; i < iters; ++i) {
        float4 nxt;
        if (i + 1 < iters) nxt = xp[(size_t)((i + 1) * 4 + wv) * 64];

        float4 x1 = shfl_xor4(cur, 1);
        float4 x2 = shfl_xor4(cur, 2);
        float4 x3 = shfl_xor4(cur, 3);
        float vm[4][4] = {{cur.x, cur.y, cur.z, cur.w},
                          {x1.x, x1.y, x1.z, x1.w},
                          {x2.x, x2.y, x2.z, x2.w},
                          {x3.x, x3.y, x3.z, x3.w}};
        float o[4] = {-b4.x, -b4.y, -b4.z, -b4.w};
#pragma unroll
        for (int r = 0; r < 4; ++r)
#pragma unroll
            for (int m = 0; m < 4; ++m)
#pragma unroll
                for (int c = 0; c < 4; ++c)
                    o[r] = fmaf(ir[r][m][c], vm[m][c], o[r]);

        op[(size_t)(i * 4 + wv) * 64] = make_float4(o[0], o[1], o[2], o[3]);
        cur = nxt;
    }
}

extern "C" void kernel_launch(void* const* d_in, const int* in_sizes, int n_in,
                              void* d_out, int out_size, void* d_ws, size_t ws_size,
                              hipStream_t stream) {
    const float* x = (const float*)d_in[0];
    float* out = (float*)d_out;
    float* ws  = (float*)d_ws;

    // pick partials block count by available ws (deterministic in inputs)
    int nblk = 0;
    if (ws_size >= (size_t)(OFF_PART + 512 * COMB) * sizeof(float)) nblk = 512;
    else if (ws_size >= (size_t)(OFF_PART + 256 * COMB) * sizeof(float)) nblk = 256;

    if (nblk == 0) {
        // atomic fallback: zero the combined accumulator region
        hipMemsetAsync(ws + OFF_TRIM, 0, COMB * sizeof(float), stream);
        k1_stats<<<512, 512, 0, stream>>>(x, ws, 0);
        k2_chol <<<16, 64, 0, stream>>>(ws, 0);
    } else {
        k1_stats<<<nblk, 512, 0, stream>>>(x, ws, nblk);
        k2_chol <<<16, 64, 0, stream>>>(ws, nblk);
    }
    k3_apply<<<1024, 256, 0, stream>>>(x, ws, out);
}

// Round 4
// 138.478 us; speedup vs baseline: 9.6152x; 3.6829x over previous
//
#include <hip/hip_runtime.h>

// DecorrelationNormalization (group whitening), x: [32,64,64,256] f32 NHWC.
// N = 131072 rows of 256 channels (1 KB each), 16 groups of m=16.
// R4: same k1/k3 as R3 (lane = contiguous float4, quad = group, shfl_xor
// exchange). Fix: the 512-partial reduction is now a parallel k2_reduce
// (entries x partial-slices) instead of 16 latency-bound waves in k2_chol.

#define NROWS   131072
#define DENOMF  131071.0f
#define EPSV    0.001f

// ws float offsets
#define OFF_INV    0        // [16][256] inv_sqrt row-major
#define OFF_BIAS   4096     // [16][16]  bias_i = sum_k inv[i][k]*mu[k]
#define OFF_TRIM   4352     // [2432] combined tri+sx (atomic fallback mode)
#define OFF_RED    8192     // [8][2432] slice-reduced partials
#define OFF_PART   27648    // [nblk][2432] per-block partials
#define COMB       2432     // 16*136 tri + 256 sx
#define NSLICE     8

__device__ __forceinline__ float4 shfl_xor4(float4 v, int m) {
    float4 r;
    r.x = __shfl_xor(v.x, m, 64);
    r.y = __shfl_xor(v.y, m, 64);
    r.z = __shfl_xor(v.z, m, 64);
    r.w = __shfl_xor(v.w, m, 64);
    return r;
}

// ---------------- Phase 1: stats ----------------
// grid nblk x 512 thr (8 waves). Block owns rows [b*rpb, (b+1)*rpb).
__global__ __launch_bounds__(512, 2) void k1_stats(const float* __restrict__ x,
                                                   float* __restrict__ ws, int nblk) {
    __shared__ float sacc[COMB];        // [0:2176) tri, [2176:2432) sx
    const int tid = threadIdx.x;
    for (int t = tid; t < COMB; t += 512) sacc[t] = 0.0f;
    __syncthreads();

    const int lane = tid & 63, wv = tid >> 6;
    const int q = lane & 3, g = lane >> 2;
    const int rpb   = NROWS / gridDim.x;
    const int iters = rpb / 8;
    const size_t rowbase = (size_t)blockIdx.x * rpb;
    const float4* xp = reinterpret_cast<const float4*>(x) + rowbase * 64 + lane;

    float acc[4][4][4];                 // [jj(own col)][m(xor)][c]
#pragma unroll
    for (int a = 0; a < 4; ++a)
#pragma unroll
        for (int b = 0; b < 4; ++b)
#pragma unroll
            for (int c = 0; c < 4; ++c) acc[a][b][c] = 0.0f;
    float s4[4] = {0.0f, 0.0f, 0.0f, 0.0f};

    float4 cur = xp[(size_t)wv * 64];
    for (int i = 0; i < iters; ++i) {
        float4 nxt;
        if (i + 1 < iters) nxt = xp[(size_t)((i + 1) * 8 + wv) * 64];

        float4 x1 = shfl_xor4(cur, 1);
        float4 x2 = shfl_xor4(cur, 2);
        float4 x3 = shfl_xor4(cur, 3);
        float vm[4][4] = {{cur.x, cur.y, cur.z, cur.w},
                          {x1.x, x1.y, x1.z, x1.w},
                          {x2.x, x2.y, x2.z, x2.w},
                          {x3.x, x3.y, x3.z, x3.w}};
        s4[0] += vm[0][0]; s4[1] += vm[0][1]; s4[2] += vm[0][2]; s4[3] += vm[0][3];
#pragma unroll
        for (int jj = 0; jj < 4; ++jj)
#pragma unroll
            for (int m = 0; m < 4; ++m)
#pragma unroll
                for (int c = 0; c < 4; ++c)
                    acc[jj][m][c] = fmaf(vm[m][c], vm[0][jj], acc[jj][m][c]);
        cur = nxt;
    }

    // fold rectangle into the triangle (i2 <= j only)
#pragma unroll
    for (int jj = 0; jj < 4; ++jj) {
        const int j = 4 * q + jj;
#pragma unroll
        for (int m = 0; m < 4; ++m) {
            const int cb = 4 * (q ^ m);
#pragma unroll
            for (int c = 0; c < 4; ++c) {
                const int i2 = cb + c;
                if (i2 <= j)
                    atomicAdd(&sacc[g * 136 + i2 * 16 - (i2 * (i2 - 1)) / 2 + (j - i2)],
                              acc[jj][m][c]);
            }
        }
        atomicAdd(&sacc[2176 + 4 * lane + jj], s4[jj]);
    }
    __syncthreads();

    if (nblk > 0) {
        float* dst = ws + OFF_PART + (size_t)blockIdx.x * COMB;
        for (int t = tid; t < COMB; t += 512) dst[t] = sacc[t];
    } else {
        for (int t = tid; t < COMB; t += 512) atomicAdd(&ws[OFF_TRIM + t], sacc[t]);
    }
}

// ---------------- Phase 2a: parallel partial reduction ----------------
// grid (ceil(COMB/256), NSLICE) x 256. Thread (t, y) sums partials
// [y*nblk/NSLICE, (y+1)*nblk/NSLICE) at entry t -> OFF_RED[y][t].
__global__ __launch_bounds__(256, 4) void k2_reduce(float* __restrict__ ws, int nblk) {
    const int t = blockIdx.x * 256 + threadIdx.x;
    if (t >= COMB) return;
    const int per = nblk / NSLICE;
    const float* p = ws + OFF_PART + (size_t)(blockIdx.y * per) * COMB + t;
    float sum = 0.0f;
#pragma unroll 8
    for (int b = 0; b < per; ++b) sum += p[(size_t)b * COMB];
    ws[OFF_RED + (size_t)blockIdx.y * COMB + t] = sum;
}

// ---------------- Phase 2b: cov -> cholesky -> inverse -> bias ----------------
// 16 blocks (one group) x 64 threads.
__global__ void k2_chol(float* __restrict__ ws, int nblk) {
    __shared__ float ct[136];
    __shared__ float cs[16];
    const int g = blockIdx.x, tid = threadIdx.x;

    if (nblk > 0) {
        for (int e = tid; e < 152; e += 64) {
            const int src = (e < 136) ? (g * 136 + e) : (2176 + g * 16 + (e - 136));
            float sum = 0.0f;
#pragma unroll
            for (int y = 0; y < NSLICE; ++y) sum += ws[OFF_RED + (size_t)y * COMB + src];
            if (e < 136) ct[e] = sum; else cs[e - 136] = sum;
        }
    } else {
        for (int e = tid; e < 152; e += 64) {
            const int src = (e < 136) ? (g * 136 + e) : (2176 + g * 16 + (e - 136));
            float v = ws[OFF_TRIM + src];
            if (e < 136) ct[e] = v; else cs[e - 136] = v;
        }
    }
    __syncthreads();

    const int ii = tid & 15;
    const float inv_denom = 1.0f / DENOMF;
    const float mu_l = cs[ii] * (1.0f / (float)NROWS);

    float arow[16];
#pragma unroll
    for (int k = 0; k < 16; ++k) {
        const int lo = (ii < k) ? ii : k;
        const int hi = (ii < k) ? k : ii;
        float sxx = ct[lo * 16 - (lo * (lo - 1)) / 2 + (hi - lo)];
        float mu_k = __shfl(mu_l, k, 64);
        float cv = (sxx - (float)NROWS * mu_l * mu_k) * inv_denom;   // /(N-1)
        cv = cv * (1.0f - EPSV) + ((k == ii) ? EPSV : 0.0f);         // shrink
        arow[k] = cv * inv_denom;                                    // faithful 2nd /(N-1)
    }

    float lrow[16];
#pragma unroll
    for (int j = 0; j < 16; ++j) {
        float diag = __shfl(arow[j], j, 64);
        float ljj  = sqrtf(diag);
        float lij  = (ii == j) ? ljj : arow[j] / ljj;
        lrow[j] = lij;
#pragma unroll
        for (int k = j + 1; k < 16; ++k) {
            float lkj = __shfl(lij, k, 64);
            arow[k] = fmaf(-lij, lkj, arow[k]);
        }
    }

    float xcol[16];
#pragma unroll
    for (int i2 = 0; i2 < 16; ++i2) {
        float ssum = (ii == i2) ? 1.0f : 0.0f;
#pragma unroll
        for (int k = 0; k < 16; ++k) {
            if (k < i2) {
                float Lik = __shfl(lrow[k], i2, 64);
                ssum = fmaf(-Lik, xcol[k], ssum);
            }
        }
        float Lii = __shfl(lrow[i2], i2, 64);
        xcol[i2] = (i2 >= ii) ? ssum / Lii : 0.0f;
    }

    float* invg = ws + OFF_INV + g * 256;
#pragma unroll
    for (int i2 = 0; i2 < 16; ++i2) {
        if (tid < 16) invg[i2 * 16 + tid] = xcol[i2];
        float bi = xcol[i2] * mu_l;
        bi += __shfl_xor(bi, 1, 64);
        bi += __shfl_xor(bi, 2, 64);
        bi += __shfl_xor(bi, 4, 64);
        bi += __shfl_xor(bi, 8, 64);
        if (tid == 0) ws[OFF_BIAS + g * 16 + i2] = bi;
    }
}

// ---------------- Phase 3: apply out = inv*x - bias ----------------
// grid 1024 x 256 thr (4 waves). inv rows 4q..4q+3 in registers, [r][m][c].
__global__ __launch_bounds__(256, 2) void k3_apply(const float* __restrict__ x,
                                                   const float* __restrict__ ws,
                                                   float* __restrict__ out) {
    const int tid = threadIdx.x, lane = tid & 63, wv = tid >> 6;
    const int q = lane & 3, g = lane >> 2;

    float ir[4][4][4];                  // [r(own row)][m(xor)][c]
    const float* invg = ws + OFF_INV + g * 256;
#pragma unroll
    for (int r = 0; r < 4; ++r)
#pragma unroll
        for (int m = 0; m < 4; ++m) {
            float4 t = *reinterpret_cast<const float4*>(invg + (4 * q + r) * 16 + 4 * (q ^ m));
            ir[r][m][0] = t.x; ir[r][m][1] = t.y; ir[r][m][2] = t.z; ir[r][m][3] = t.w;
        }
    float4 b4 = *reinterpret_cast<const float4*>(ws + OFF_BIAS + g * 16 + 4 * q);

    const int rpb   = NROWS / gridDim.x;   // 128
    const int iters = rpb / 4;             // 32
    const size_t rowbase = (size_t)blockIdx.x * rpb;
    const float4* xp = reinterpret_cast<const float4*>(x) + rowbase * 64 + lane;
    float4*       op = reinterpret_cast<float4*>(out)     + rowbase * 64 + lane;

    float4 cur = xp[(size_t)wv * 64];
    for (int i = 0; i < iters; ++i) {
        float4 nxt;
        if (i + 1 < iters) nxt = xp[(size_t)((i + 1) * 4 + wv) * 64];

        float4 x1 = shfl_xor4(cur, 1);
        float4 x2 = shfl_xor4(cur, 2);
        float4 x3 = shfl_xor4(cur, 3);
        float vm[4][4] = {{cur.x, cur.y, cur.z, cur.w},
                          {x1.x, x1.y, x1.z, x1.w},
                          {x2.x, x2.y, x2.z, x2.w},
                          {x3.x, x3.y, x3.z, x3.w}};
        float o[4] = {-b4.x, -b4.y, -b4.z, -b4.w};
#pragma unroll
        for (int r = 0; r < 4; ++r)
#pragma unroll
            for (int m = 0; m < 4; ++m)
#pragma unroll
                for (int c = 0; c < 4; ++c)
                    o[r] = fmaf(ir[r][m][c], vm[m][c], o[r]);

        op[(size_t)(i * 4 + wv) * 64] = make_float4(o[0], o[1], o[2], o[3]);
        cur = nxt;
    }
}

extern "C" void kernel_launch(void* const* d_in, const int* in_sizes, int n_in,
                              void* d_out, int out_size, void* d_ws, size_t ws_size,
                              hipStream_t stream) {
    const float* x = (const float*)d_in[0];
    float* out = (float*)d_out;
    float* ws  = (float*)d_ws;

    int nblk = 0;
    if (ws_size >= (size_t)(OFF_PART + 512 * COMB) * sizeof(float)) nblk = 512;
    else if (ws_size >= (size_t)(OFF_PART + 256 * COMB) * sizeof(float)) nblk = 256;

    if (nblk == 0) {
        hipMemsetAsync(ws + OFF_TRIM, 0, COMB * sizeof(float), stream);
        k1_stats<<<512, 512, 0, stream>>>(x, ws, 0);
        k2_chol <<<16, 64, 0, stream>>>(ws, 0);
    } else {
        k1_stats<<<nblk, 512, 0, stream>>>(x, ws, nblk);
        dim3 rg((COMB + 255) / 256, NSLICE);
        k2_reduce<<<rg, 256, 0, stream>>>(ws, nblk);
        k2_chol <<<16, 64, 0, stream>>>(ws, nblk);
    }
    k3_apply<<<1024, 256, 0, stream>>>(x, ws, out);
}